// Round 12
// baseline (1773.176 us; speedup 1.0000x reference)
//
#include <hip/hip_runtime.h>

// ---- problem constants ----
#define NE 16
#define DD 2048
#define HH 1408
#define HSH 2816
#define TOPK 6
#define TT 4096

typedef __bf16 bf16x8 __attribute__((ext_vector_type(8)));
typedef __bf16 bf16x4 __attribute__((ext_vector_type(4)));
typedef float f32x4 __attribute__((ext_vector_type(4)));

typedef const __attribute__((address_space(1))) void gvoid_t;
typedef __attribute__((address_space(3))) void lvoid_t;

__device__ __forceinline__ void gll16(const void* g, void* l) {
  __builtin_amdgcn_global_load_lds((gvoid_t*)g, (lvoid_t*)l, 16, 0, 0);
}

// ---------------- merged fp32 -> bf16 convert (7 segments, 1 launch) ----------------
struct Cvt7 {
  const float* src[7];
  __bf16* dst[7];
  long off[8];  // prefix sums in float4 units
};
__global__ __launch_bounds__(256) void k_cvt_all(Cvt7 c) {
  long i = (long)blockIdx.x * blockDim.x + threadIdx.x;
  long stride = (long)gridDim.x * blockDim.x;
  long total = c.off[7];
  for (; i < total; i += stride) {
    int seg = 0;
    while (i >= c.off[seg + 1]) ++seg;
    long j = i - c.off[seg];
    float4 v = ((const float4*)c.src[seg])[j];
    bf16x4 o = { (__bf16)v.x, (__bf16)v.y, (__bf16)v.z, (__bf16)v.w };
    ((bf16x4*)c.dst[seg])[j] = o;
  }
}

// ---------------- gate: softmax + biased top-6 ----------------
__global__ __launch_bounds__(256) void k_gate(
    const float* __restrict__ x, const float* __restrict__ gw,
    const float* __restrict__ gb, float* __restrict__ cw,
    int* __restrict__ counts, int* __restrict__ lists,
    int* __restrict__ tok_e, int* __restrict__ tok_pos) {
  int t = blockIdx.x;
  int lane = threadIdx.x & 63, wave = threadIdx.x >> 6;
  __shared__ float sc[NE];
  const float* xt = x + (size_t)t * DD;
  for (int ei = 0; ei < 4; ++ei) {
    int e = wave * 4 + ei;
    const float* ge = gw + (size_t)e * DD;
    float s = 0.f;
    for (int j = 0; j < DD / 64; ++j) s += xt[lane + 64 * j] * ge[lane + 64 * j];
    for (int o = 32; o; o >>= 1) s += __shfl_xor(s, o);
    if (lane == 0) sc[e] = s;
  }
  __syncthreads();
  if (threadIdx.x == 0) {
    float p[NE], b[NE];
    float m = -1e30f;
    for (int e = 0; e < NE; ++e) m = fmaxf(m, sc[e]);
    float sum = 0.f;
    for (int e = 0; e < NE; ++e) { p[e] = expf(sc[e] - m); sum += p[e]; }
    float inv = 1.f / sum;
    for (int e = 0; e < NE; ++e) { p[e] *= inv; b[e] = p[e] + gb[e]; }
    float out[NE];
    bool used[NE];
    for (int e = 0; e < NE; ++e) { out[e] = 0.f; used[e] = false; }
    for (int k = 0; k < TOPK; ++k) {
      int best = -1; float bv = -1e30f;
      for (int e = 0; e < NE; ++e)
        if (!used[e] && b[e] > bv) { bv = b[e]; best = e; }
      used[best] = true;
      out[best] = p[best];  // ROUTE_SCALE = 1.0
      int pos = atomicAdd(&counts[best], 1);
      lists[best * TT + pos] = t;
      tok_e[t * TOPK + k] = best;
      tok_pos[t * TOPK + k] = pos;
    }
    for (int e = 0; e < NE; ++e) cw[(size_t)t * NE + e] = out[e];
  }
}

__global__ void k_offsets(const int* __restrict__ counts, int* __restrict__ offs) {
  if (threadIdx.x == 0) {
    int a = 0;
    for (int e = 0; e < NE; ++e) { offs[e] = a; a += counts[e]; }
    offs[NE] = a;
  }
}

// =====================================================================
// Merged GEMM1 (routed z<16, shared z==16): SwiGLU up-proj.
// R12: same 256-row 8-wave structure as R11, but launch_bounds(512,2)
// -> reg cap 256/wave (was 128 at (512,4): borderline -> fragment
// SPILL, 1.07 GB scratch writes, R11 post-mortem). At ~128 actual regs
// HW still schedules 4 waves/SIMD = 2 blocks/CU = 50% occ; LDS 2x48KB
// fits. Never set the cap at/below the kernel's actual need (R8/R11).
// =====================================================================
__global__ __launch_bounds__(512, 2) void k_g1m(
    const __bf16* __restrict__ xb,
    const __bf16* __restrict__ W1r, const float* __restrict__ B1r,
    const __bf16* __restrict__ W3r, const float* __restrict__ B3r,
    const __bf16* __restrict__ W1s, const float* __restrict__ B1s,
    const __bf16* __restrict__ W3s, const float* __restrict__ B3s,
    __bf16* __restrict__ Hr, __bf16* __restrict__ Hs,
    const int* __restrict__ counts, const int* __restrict__ offs,
    const int* __restrict__ lists) {
  int z = blockIdx.z;
  bool sh = (z == NE);
  int gxmax = sh ? (HSH / 64) : (HH / 64);
  if ((int)blockIdx.x >= gxmax) return;
  int count = sh ? TT : counts[z];
  int m0 = blockIdx.y * 256;
  if (m0 >= count) return;
  int n0 = blockIdx.x * 64;
  int Hdim = sh ? HSH : HH;
  const __bf16* W1e = sh ? W1s : W1r + (size_t)z * HH * DD;
  const __bf16* W3e = sh ? W3s : W3r + (size_t)z * HH * DD;
  const float* B1e = sh ? B1s : B1r + (size_t)z * HH;
  const float* B3e = sh ? B3s : B3r + (size_t)z * HH;
  __bf16* Hout = sh ? Hs : Hr;
  int hbase = sh ? 0 : offs[z];
  const int* liste = lists + (size_t)z * TT;

  __shared__ __bf16 At[256 * 64];   // 32768 B
  __shared__ __bf16 B1t[64 * 64];   //  8192 B
  __shared__ __bf16 B3t[64 * 64];   //  8192 B  => 49152 B total

  int tid = threadIdx.x, lane = tid & 63, w = tid >> 6;  // 8 waves
  int lr8 = lane >> 3;         // 0..7 row within 8-row chunk
  int lc8 = (lane & 7) * 8;    // col start (bf16 elems)

  // per-lane gathered token ids: 4 chunks of 64 rows, each wave owns 8 rows/chunk
  int tokr[4];
  #pragma unroll
  for (int c = 0; c < 4; ++c) {
    int row = m0 + c * 64 + w * 8 + lr8;
    if (row >= count) row = count - 1;
    tokr[c] = sh ? row : liste[row];
  }

  int wm = w >> 1, wn = w & 1;   // 4m x 2n wave grid; wave tile 64x32/matrix
  f32x4 acc1[4][2] = {};
  f32x4 acc3[4][2] = {};
  int fr = lane & 15;
  int fk = (lane >> 4) * 8;

  for (int k0 = 0; k0 < DD; k0 += 64) {
    #pragma unroll
    for (int c = 0; c < 4; ++c) {
      int br = c * 64 + w * 8;
      gll16(xb + (size_t)tokr[c] * DD + k0 + lc8, &At[br * 64]);
    }
    {
      int br = w * 8;  // 8 waves x 8 rows = 64 rows
      gll16(W1e + (size_t)(n0 + br + lr8) * DD + k0 + lc8, &B1t[br * 64]);
      gll16(W3e + (size_t)(n0 + br + lr8) * DD + k0 + lc8, &B3t[br * 64]);
    }
    __syncthreads();
    #pragma unroll
    for (int kk = 0; kk < 2; ++kk) {
      bf16x8 af[4], b1f[2], b3f[2];
      #pragma unroll
      for (int m = 0; m < 4; ++m)
        af[m] = *(const bf16x8*)&At[(wm * 64 + m * 16 + fr) * 64 + kk * 32 + fk];
      #pragma unroll
      for (int n = 0; n < 2; ++n) {
        b1f[n] = *(const bf16x8*)&B1t[(wn * 32 + n * 16 + fr) * 64 + kk * 32 + fk];
        b3f[n] = *(const bf16x8*)&B3t[(wn * 32 + n * 16 + fr) * 64 + kk * 32 + fk];
      }
      #pragma unroll
      for (int m = 0; m < 4; ++m)
        #pragma unroll
        for (int n = 0; n < 2; ++n) {
          acc1[m][n] = __builtin_amdgcn_mfma_f32_16x16x32_bf16(af[m], b1f[n], acc1[m][n], 0, 0, 0);
          acc3[m][n] = __builtin_amdgcn_mfma_f32_16x16x32_bf16(af[m], b3f[n], acc3[m][n], 0, 0, 0);
        }
    }
    __syncthreads();
  }
  // epilogue: silu(h1+b1)*(h3+b3) -> bf16
  #pragma unroll
  for (int m = 0; m < 4; ++m)
    #pragma unroll
    for (int n = 0; n < 2; ++n)
      #pragma unroll
      for (int j = 0; j < 4; ++j) {
        int rl = wm * 64 + m * 16 + (lane >> 4) * 4 + j;
        int s = m0 + rl;
        if (s < count) {
          int col = n0 + wn * 32 + n * 16 + fr;
          float h1 = acc1[m][n][j] + B1e[col];
          float h3 = acc3[m][n][j] + B3e[col];
          float v = h1 / (1.f + expf(-h1)) * h3;
          Hout[(size_t)(hbase + s) * Hdim + col] = (__bf16)v;
        }
      }
}

// =====================================================================
// Merged GEMM2 (routed z<16 -> bf16 Ybuf, shared z==16 -> fp32 out).
// R9 config UNCHANGED.
// =====================================================================
__global__ __launch_bounds__(256, 4) void k_g2m(
    const __bf16* __restrict__ Hr, const __bf16* __restrict__ Hs,
    const __bf16* __restrict__ W2r, const float* __restrict__ B2r,
    const __bf16* __restrict__ W2s, const float* __restrict__ B2s,
    float* __restrict__ out, __bf16* __restrict__ Ybuf,
    const int* __restrict__ counts, const int* __restrict__ offs) {
  int z = blockIdx.z;
  bool sh = (z == NE);
  int Kd = sh ? HSH : HH;
  int count = sh ? TT : counts[z];
  int m0 = blockIdx.y * 128;
  if (m0 >= count) return;
  int n0 = blockIdx.x * 128;
  int hbase = sh ? 0 : offs[z];
  const __bf16* Ae = sh ? Hs : Hr + (size_t)hbase * HH;
  const __bf16* W2e = sh ? W2s : W2r + (size_t)z * DD * HH;
  const float* B2e = sh ? B2s : B2r + (size_t)z * DD;

  __shared__ __bf16 At[128 * 64];
  __shared__ __bf16 Bt[128 * 64];

  int tid = threadIdx.x, lane = tid & 63, wave = tid >> 6;
  int wm = wave >> 1, wn = wave & 1;
  f32x4 acc[4][4] = {};
  int lr8 = lane >> 3;
  int lc8 = (lane & 7) * 8;
  int fr = lane & 15;
  int fk = (lane >> 4) * 8;

  for (int k0 = 0; k0 < Kd; k0 += 64) {
    #pragma unroll
    for (int c = 0; c < 4; ++c) {
      int br = c * 32 + wave * 8;
      int sr = m0 + br + lr8;
      if (sr >= count) sr = count - 1;
      gll16(Ae + (size_t)sr * Kd + k0 + lc8, &At[br * 64]);
      gll16(W2e + (size_t)(n0 + br + lr8) * Kd + k0 + lc8, &Bt[br * 64]);
    }
    __syncthreads();
    #pragma unroll
    for (int kk = 0; kk < 2; ++kk) {
      bf16x8 af[4], bf[4];
      #pragma unroll
      for (int m = 0; m < 4; ++m)
        af[m] = *(const bf16x8*)&At[(wm * 64 + m * 16 + fr) * 64 + kk * 32 + fk];
      #pragma unroll
      for (int n = 0; n < 4; ++n)
        bf[n] = *(const bf16x8*)&Bt[(wn * 64 + n * 16 + fr) * 64 + kk * 32 + fk];
      #pragma unroll
      for (int m = 0; m < 4; ++m)
        #pragma unroll
        for (int n = 0; n < 4; ++n)
          acc[m][n] = __builtin_amdgcn_mfma_f32_16x16x32_bf16(af[m], bf[n], acc[m][n], 0, 0, 0);
    }
    __syncthreads();
  }
  #pragma unroll
  for (int m = 0; m < 4; ++m)
    #pragma unroll
    for (int n = 0; n < 4; ++n)
      #pragma unroll
      for (int j = 0; j < 4; ++j) {
        int rl = wm * 64 + m * 16 + (lane >> 4) * 4 + j;
        int s = m0 + rl;
        if (s < count) {
          int d = n0 + wn * 64 + n * 16 + fr;
          float v = acc[m][n][j] + B2e[d];
          if (!sh)
            Ybuf[(size_t)(hbase + s) * DD + d] = (__bf16)v;
          else
            out[(size_t)s * DD + d] = v;
        }
      }
}

// ---------------- combine: out[t] += sum_k cw * Ybuf[row_k] ----------------
__global__ __launch_bounds__(256) void k_combine(
    const __bf16* __restrict__ Ybuf, const float* __restrict__ cw,
    const int* __restrict__ offs, const int* __restrict__ tok_e,
    const int* __restrict__ tok_pos, float* __restrict__ out) {
  int t = blockIdx.x;
  int tid = threadIdx.x;
  __shared__ int rws[TOPK];
  __shared__ float wsh[TOPK];
  if (tid < TOPK) {
    int e = tok_e[t * TOPK + tid];
    rws[tid] = offs[e] + tok_pos[t * TOPK + tid];
    wsh[tid] = cw[(size_t)t * NE + e];
  }
  __syncthreads();
  int d0 = tid * 8;
  float a[8];
  float4 o0 = *(const float4*)&out[(size_t)t * DD + d0];
  float4 o1 = *(const float4*)&out[(size_t)t * DD + d0 + 4];
  a[0] = o0.x; a[1] = o0.y; a[2] = o0.z; a[3] = o0.w;
  a[4] = o1.x; a[5] = o1.y; a[6] = o1.z; a[7] = o1.w;
  #pragma unroll
  for (int k = 0; k < TOPK; ++k) {
    bf16x8 v = *(const bf16x8*)&Ybuf[(size_t)rws[k] * DD + d0];
    float w = wsh[k];
    #pragma unroll
    for (int j = 0; j < 8; ++j) a[j] += w * (float)v[j];
  }
  float4 r0 = { a[0], a[1], a[2], a[3] };
  float4 r1 = { a[4], a[5], a[6], a[7] };
  *(float4*)&out[(size_t)t * DD + d0] = r0;
  *(float4*)&out[(size_t)t * DD + d0 + 4] = r1;
}

// ---------------- launch ----------------
extern "C" void kernel_launch(void* const* d_in, const int* in_sizes, int n_in,
                              void* d_out, int out_size, void* d_ws, size_t ws_size,
                              hipStream_t stream) {
  const float* x      = (const float*)d_in[0];
  const float* gate_w = (const float*)d_in[1];
  const float* gate_b = (const float*)d_in[2];
  const float* w1     = (const float*)d_in[3];
  const float* b1     = (const float*)d_in[4];
  const float* w2     = (const float*)d_in[5];
  const float* b2     = (const float*)d_in[6];
  const float* w3     = (const float*)d_in[7];
  const float* b3     = (const float*)d_in[8];
  const float* ws1    = (const float*)d_in[9];
  const float* bs1    = (const float*)d_in[10];
  const float* ws2    = (const float*)d_in[11];
  const float* bs2    = (const float*)d_in[12];
  const float* ws3    = (const float*)d_in[13];
  const float* bs3    = (const float*)d_in[14];
  float* outp = (float*)d_out;

  char* ws = (char*)d_ws;
  size_t off = 0;
  auto take = [&](size_t bytes) { char* p = ws + off; off += (bytes + 255) & ~(size_t)255; return p; };
  __bf16* xb   = (__bf16*)take((size_t)TT * DD * 2);
  __bf16* w1b  = (__bf16*)take((size_t)NE * HH * DD * 2);
  __bf16* w3b  = (__bf16*)take((size_t)NE * HH * DD * 2);
  __bf16* w2b  = (__bf16*)take((size_t)NE * DD * HH * 2);
  __bf16* ws1b = (__bf16*)take((size_t)HSH * DD * 2);
  __bf16* ws3b = (__bf16*)take((size_t)HSH * DD * 2);
  __bf16* ws2b = (__bf16*)take((size_t)DD * HSH * 2);
  __bf16* Hbuf = (__bf16*)take((size_t)TT * TOPK * HH * 2);
  __bf16* Sbuf = (__bf16*)take((size_t)TT * HSH * 2);
  float*  cw   = (float*)take((size_t)TT * NE * 4);
  int*    lists  = (int*)take((size_t)NE * TT * 4);
  int*    tok_e  = (int*)take((size_t)TT * TOPK * 4);
  int*    tok_pos= (int*)take((size_t)TT * TOPK * 4);
  int*    counts = (int*)take(64);
  int*    offs   = (int*)take(128);
  // Ybuf (100.7 MB) aliases w1b (115.3 MB): w1b dead after k_g1m completes.
  __bf16* Ybuf = w1b;

  hipMemsetAsync(counts, 0, NE * sizeof(int), stream);

  Cvt7 c;
  const float* srcs[7] = { x, w1, w3, w2, ws1, ws3, ws2 };
  __bf16* dsts[7] = { xb, w1b, w3b, w2b, ws1b, ws3b, ws2b };
  long sz4[7] = { (long)TT * DD / 4, (long)NE * HH * DD / 4, (long)NE * HH * DD / 4,
                  (long)NE * DD * HH / 4, (long)HSH * DD / 4, (long)HSH * DD / 4,
                  (long)DD * HSH / 4 };
  c.off[0] = 0;
  for (int i = 0; i < 7; ++i) { c.src[i] = srcs[i]; c.dst[i] = dsts[i]; c.off[i + 1] = c.off[i] + sz4[i]; }
  k_cvt_all<<<4096, 256, 0, stream>>>(c);

  k_gate<<<TT, 256, 0, stream>>>(x, gate_w, gate_b, cw, counts, lists, tok_e, tok_pos);
  k_offsets<<<1, 64, 0, stream>>>(counts, offs);

  // merged up-proj: 256-row m-tiles, 8-wave blocks (grid.y = 16)
  k_g1m<<<dim3(HSH / 64, TT / 256, NE + 1), 512, 0, stream>>>(
      xb, w1b, b1, w3b, b3, ws1b, bs1, ws3b, bs3,
      Hbuf, Sbuf, counts, offs, lists);
  // merged down-proj: z<16 routed -> Ybuf, z==16 shared -> out (R9 config)
  k_g2m<<<dim3(DD / 128, TT / 128, NE + 1), 256, 0, stream>>>(
      Hbuf, Sbuf, w2b, b2, ws2b, bs2, outp, Ybuf, counts, offs);
  // gather-combine routed contributions into out
  k_combine<<<TT, 256, 0, stream>>>(Ybuf, cw, offs, tok_e, tok_pos, outp);
}

// Round 13
// 1296.156 us; speedup vs baseline: 1.3680x; 1.3680x over previous
//
#include <hip/hip_runtime.h>

// ---- problem constants ----
#define NE 16
#define DD 2048
#define HH 1408
#define HSH 2816
#define TOPK 6
#define TT 4096

typedef __bf16 bf16x8 __attribute__((ext_vector_type(8)));
typedef __bf16 bf16x4 __attribute__((ext_vector_type(4)));
typedef float f32x4 __attribute__((ext_vector_type(4)));

typedef const __attribute__((address_space(1))) void gvoid_t;
typedef __attribute__((address_space(3))) void lvoid_t;

__device__ __forceinline__ void gll16(const void* g, void* l) {
  __builtin_amdgcn_global_load_lds((gvoid_t*)g, (lvoid_t*)l, 16, 0, 0);
}

// ---------------- merged fp32 -> bf16 convert (7 segments, 1 launch) ----------------
struct Cvt7 {
  const float* src[7];
  __bf16* dst[7];
  long off[8];  // prefix sums in float4 units
};
__global__ __launch_bounds__(256) void k_cvt_all(Cvt7 c) {
  long i = (long)blockIdx.x * blockDim.x + threadIdx.x;
  long stride = (long)gridDim.x * blockDim.x;
  long total = c.off[7];
  for (; i < total; i += stride) {
    int seg = 0;
    while (i >= c.off[seg + 1]) ++seg;
    long j = i - c.off[seg];
    float4 v = ((const float4*)c.src[seg])[j];
    bf16x4 o = { (__bf16)v.x, (__bf16)v.y, (__bf16)v.z, (__bf16)v.w };
    ((bf16x4*)c.dst[seg])[j] = o;
  }
}

// ---------------- gate: softmax + biased top-6 ----------------
__global__ __launch_bounds__(256) void k_gate(
    const float* __restrict__ x, const float* __restrict__ gw,
    const float* __restrict__ gb, float* __restrict__ cw,
    int* __restrict__ counts, int* __restrict__ lists,
    int* __restrict__ tok_e, int* __restrict__ tok_pos) {
  int t = blockIdx.x;
  int lane = threadIdx.x & 63, wave = threadIdx.x >> 6;
  __shared__ float sc[NE];
  const float* xt = x + (size_t)t * DD;
  for (int ei = 0; ei < 4; ++ei) {
    int e = wave * 4 + ei;
    const float* ge = gw + (size_t)e * DD;
    float s = 0.f;
    for (int j = 0; j < DD / 64; ++j) s += xt[lane + 64 * j] * ge[lane + 64 * j];
    for (int o = 32; o; o >>= 1) s += __shfl_xor(s, o);
    if (lane == 0) sc[e] = s;
  }
  __syncthreads();
  if (threadIdx.x == 0) {
    float p[NE], b[NE];
    float m = -1e30f;
    for (int e = 0; e < NE; ++e) m = fmaxf(m, sc[e]);
    float sum = 0.f;
    for (int e = 0; e < NE; ++e) { p[e] = expf(sc[e] - m); sum += p[e]; }
    float inv = 1.f / sum;
    for (int e = 0; e < NE; ++e) { p[e] *= inv; b[e] = p[e] + gb[e]; }
    float out[NE];
    bool used[NE];
    for (int e = 0; e < NE; ++e) { out[e] = 0.f; used[e] = false; }
    for (int k = 0; k < TOPK; ++k) {
      int best = -1; float bv = -1e30f;
      for (int e = 0; e < NE; ++e)
        if (!used[e] && b[e] > bv) { bv = b[e]; best = e; }
      used[best] = true;
      out[best] = p[best];  // ROUTE_SCALE = 1.0
      int pos = atomicAdd(&counts[best], 1);
      lists[best * TT + pos] = t;
      tok_e[t * TOPK + k] = best;
      tok_pos[t * TOPK + k] = pos;
    }
    for (int e = 0; e < NE; ++e) cw[(size_t)t * NE + e] = out[e];
  }
}

__global__ void k_offsets(const int* __restrict__ counts, int* __restrict__ offs) {
  if (threadIdx.x == 0) {
    int a = 0;
    for (int e = 0; e < NE; ++e) { offs[e] = a; a += counts[e]; }
    offs[NE] = a;
  }
}

// =====================================================================
// Merged GEMM1 (routed z<16, shared z==16): SwiGLU up-proj.
// R9 config (established optimum of this design space, 532 us measured):
// tile 128x(64+64 fused), BK=64, 4 waves (2x2), per-lane tokr regs,
// LDS exactly 32768 B, launch_bounds(256,4).
// Probed and rejected alternatives: BN=128 (R4, FETCH unchanged, occ
// down), M=256 tiles at 4w/(256,2) (R10), 8w/(512,4) (R11, spill),
// 8w/(512,2) (R12, fill-rate collapse). Occupancy hints above register
// need cause accumulator spill (R8: 3 GB scratch writes).
// =====================================================================
__global__ __launch_bounds__(256, 4) void k_g1m(
    const __bf16* __restrict__ xb,
    const __bf16* __restrict__ W1r, const float* __restrict__ B1r,
    const __bf16* __restrict__ W3r, const float* __restrict__ B3r,
    const __bf16* __restrict__ W1s, const float* __restrict__ B1s,
    const __bf16* __restrict__ W3s, const float* __restrict__ B3s,
    __bf16* __restrict__ Hr, __bf16* __restrict__ Hs,
    const int* __restrict__ counts, const int* __restrict__ offs,
    const int* __restrict__ lists) {
  int z = blockIdx.z;
  bool sh = (z == NE);
  int gxmax = sh ? (HSH / 64) : (HH / 64);
  if ((int)blockIdx.x >= gxmax) return;
  int count = sh ? TT : counts[z];
  int m0 = blockIdx.y * 128;
  if (m0 >= count) return;
  int n0 = blockIdx.x * 64;
  int Hdim = sh ? HSH : HH;
  const __bf16* W1e = sh ? W1s : W1r + (size_t)z * HH * DD;
  const __bf16* W3e = sh ? W3s : W3r + (size_t)z * HH * DD;
  const float* B1e = sh ? B1s : B1r + (size_t)z * HH;
  const float* B3e = sh ? B3s : B3r + (size_t)z * HH;
  __bf16* Hout = sh ? Hs : Hr;
  int hbase = sh ? 0 : offs[z];
  const int* liste = lists + (size_t)z * TT;

  __shared__ __bf16 At[128 * 64];   // 16384 B
  __shared__ __bf16 B1t[64 * 64];   //  8192 B
  __shared__ __bf16 B3t[64 * 64];   //  8192 B  => 32768 B total

  int tid = threadIdx.x, lane = tid & 63, wave = tid >> 6;
  int lr8 = lane >> 3;         // 0..7 row within 8-row chunk
  int lc8 = (lane & 7) * 8;    // col start (bf16 elems)

  // per-lane gathered token ids (replaces rowtok LDS)
  int tokr[4];
  #pragma unroll
  for (int c = 0; c < 4; ++c) {
    int row = m0 + c * 32 + wave * 8 + lr8;
    if (row >= count) row = count - 1;
    tokr[c] = sh ? row : liste[row];
  }

  int wm = wave >> 1, wn = wave & 1;
  f32x4 acc1[4][2] = {};
  f32x4 acc3[4][2] = {};
  int fr = lane & 15;
  int fk = (lane >> 4) * 8;

  for (int k0 = 0; k0 < DD; k0 += 64) {
    #pragma unroll
    for (int c = 0; c < 4; ++c) {
      int br = c * 32 + wave * 8;
      gll16(xb + (size_t)tokr[c] * DD + k0 + lc8, &At[br * 64]);
    }
    #pragma unroll
    for (int c = 0; c < 2; ++c) {
      int br = c * 32 + wave * 8;
      gll16(W1e + (size_t)(n0 + br + lr8) * DD + k0 + lc8, &B1t[br * 64]);
      gll16(W3e + (size_t)(n0 + br + lr8) * DD + k0 + lc8, &B3t[br * 64]);
    }
    __syncthreads();
    #pragma unroll
    for (int kk = 0; kk < 2; ++kk) {
      bf16x8 af[4], b1f[2], b3f[2];
      #pragma unroll
      for (int m = 0; m < 4; ++m)
        af[m] = *(const bf16x8*)&At[(wm * 64 + m * 16 + fr) * 64 + kk * 32 + fk];
      #pragma unroll
      for (int n = 0; n < 2; ++n) {
        b1f[n] = *(const bf16x8*)&B1t[(wn * 32 + n * 16 + fr) * 64 + kk * 32 + fk];
        b3f[n] = *(const bf16x8*)&B3t[(wn * 32 + n * 16 + fr) * 64 + kk * 32 + fk];
      }
      #pragma unroll
      for (int m = 0; m < 4; ++m)
        #pragma unroll
        for (int n = 0; n < 2; ++n) {
          acc1[m][n] = __builtin_amdgcn_mfma_f32_16x16x32_bf16(af[m], b1f[n], acc1[m][n], 0, 0, 0);
          acc3[m][n] = __builtin_amdgcn_mfma_f32_16x16x32_bf16(af[m], b3f[n], acc3[m][n], 0, 0, 0);
        }
    }
    __syncthreads();
  }
  // epilogue: silu(h1+b1)*(h3+b3) -> bf16
  #pragma unroll
  for (int m = 0; m < 4; ++m)
    #pragma unroll
    for (int n = 0; n < 2; ++n)
      #pragma unroll
      for (int j = 0; j < 4; ++j) {
        int rl = wm * 64 + m * 16 + (lane >> 4) * 4 + j;
        int s = m0 + rl;
        if (s < count) {
          int col = n0 + wn * 32 + n * 16 + fr;
          float h1 = acc1[m][n][j] + B1e[col];
          float h3 = acc3[m][n][j] + B3e[col];
          float v = h1 / (1.f + expf(-h1)) * h3;
          Hout[(size_t)(hbase + s) * Hdim + col] = (__bf16)v;
        }
      }
}

// =====================================================================
// Merged GEMM2 (routed z<16 -> bf16 Ybuf, shared z==16 -> fp32 out).
// R9 config: tile 128x128, acc 4x4, BK=64, no atomics.
// =====================================================================
__global__ __launch_bounds__(256, 4) void k_g2m(
    const __bf16* __restrict__ Hr, const __bf16* __restrict__ Hs,
    const __bf16* __restrict__ W2r, const float* __restrict__ B2r,
    const __bf16* __restrict__ W2s, const float* __restrict__ B2s,
    float* __restrict__ out, __bf16* __restrict__ Ybuf,
    const int* __restrict__ counts, const int* __restrict__ offs) {
  int z = blockIdx.z;
  bool sh = (z == NE);
  int Kd = sh ? HSH : HH;
  int count = sh ? TT : counts[z];
  int m0 = blockIdx.y * 128;
  if (m0 >= count) return;
  int n0 = blockIdx.x * 128;
  int hbase = sh ? 0 : offs[z];
  const __bf16* Ae = sh ? Hs : Hr + (size_t)hbase * HH;
  const __bf16* W2e = sh ? W2s : W2r + (size_t)z * DD * HH;
  const float* B2e = sh ? B2s : B2r + (size_t)z * DD;

  __shared__ __bf16 At[128 * 64];
  __shared__ __bf16 Bt[128 * 64];

  int tid = threadIdx.x, lane = tid & 63, wave = tid >> 6;
  int wm = wave >> 1, wn = wave & 1;
  f32x4 acc[4][4] = {};
  int lr8 = lane >> 3;
  int lc8 = (lane & 7) * 8;
  int fr = lane & 15;
  int fk = (lane >> 4) * 8;

  for (int k0 = 0; k0 < Kd; k0 += 64) {
    #pragma unroll
    for (int c = 0; c < 4; ++c) {
      int br = c * 32 + wave * 8;
      int sr = m0 + br + lr8;
      if (sr >= count) sr = count - 1;
      gll16(Ae + (size_t)sr * Kd + k0 + lc8, &At[br * 64]);
      gll16(W2e + (size_t)(n0 + br + lr8) * Kd + k0 + lc8, &Bt[br * 64]);
    }
    __syncthreads();
    #pragma unroll
    for (int kk = 0; kk < 2; ++kk) {
      bf16x8 af[4], bf[4];
      #pragma unroll
      for (int m = 0; m < 4; ++m)
        af[m] = *(const bf16x8*)&At[(wm * 64 + m * 16 + fr) * 64 + kk * 32 + fk];
      #pragma unroll
      for (int n = 0; n < 4; ++n)
        bf[n] = *(const bf16x8*)&Bt[(wn * 64 + n * 16 + fr) * 64 + kk * 32 + fk];
      #pragma unroll
      for (int m = 0; m < 4; ++m)
        #pragma unroll
        for (int n = 0; n < 4; ++n)
          acc[m][n] = __builtin_amdgcn_mfma_f32_16x16x32_bf16(af[m], bf[n], acc[m][n], 0, 0, 0);
    }
    __syncthreads();
  }
  #pragma unroll
  for (int m = 0; m < 4; ++m)
    #pragma unroll
    for (int n = 0; n < 4; ++n)
      #pragma unroll
      for (int j = 0; j < 4; ++j) {
        int rl = wm * 64 + m * 16 + (lane >> 4) * 4 + j;
        int s = m0 + rl;
        if (s < count) {
          int d = n0 + wn * 64 + n * 16 + fr;
          float v = acc[m][n][j] + B2e[d];
          if (!sh)
            Ybuf[(size_t)(hbase + s) * DD + d] = (__bf16)v;
          else
            out[(size_t)s * DD + d] = v;
        }
      }
}

// ---------------- combine: out[t] += sum_k cw * Ybuf[row_k] ----------------
__global__ __launch_bounds__(256) void k_combine(
    const __bf16* __restrict__ Ybuf, const float* __restrict__ cw,
    const int* __restrict__ offs, const int* __restrict__ tok_e,
    const int* __restrict__ tok_pos, float* __restrict__ out) {
  int t = blockIdx.x;
  int tid = threadIdx.x;
  __shared__ int rws[TOPK];
  __shared__ float wsh[TOPK];
  if (tid < TOPK) {
    int e = tok_e[t * TOPK + tid];
    rws[tid] = offs[e] + tok_pos[t * TOPK + tid];
    wsh[tid] = cw[(size_t)t * NE + e];
  }
  __syncthreads();
  int d0 = tid * 8;
  float a[8];
  float4 o0 = *(const float4*)&out[(size_t)t * DD + d0];
  float4 o1 = *(const float4*)&out[(size_t)t * DD + d0 + 4];
  a[0] = o0.x; a[1] = o0.y; a[2] = o0.z; a[3] = o0.w;
  a[4] = o1.x; a[5] = o1.y; a[6] = o1.z; a[7] = o1.w;
  #pragma unroll
  for (int k = 0; k < TOPK; ++k) {
    bf16x8 v = *(const bf16x8*)&Ybuf[(size_t)rws[k] * DD + d0];
    float w = wsh[k];
    #pragma unroll
    for (int j = 0; j < 8; ++j) a[j] += w * (float)v[j];
  }
  float4 r0 = { a[0], a[1], a[2], a[3] };
  float4 r1 = { a[4], a[5], a[6], a[7] };
  *(float4*)&out[(size_t)t * DD + d0] = r0;
  *(float4*)&out[(size_t)t * DD + d0 + 4] = r1;
}

// ---------------- launch ----------------
extern "C" void kernel_launch(void* const* d_in, const int* in_sizes, int n_in,
                              void* d_out, int out_size, void* d_ws, size_t ws_size,
                              hipStream_t stream) {
  const float* x      = (const float*)d_in[0];
  const float* gate_w = (const float*)d_in[1];
  const float* gate_b = (const float*)d_in[2];
  const float* w1     = (const float*)d_in[3];
  const float* b1     = (const float*)d_in[4];
  const float* w2     = (const float*)d_in[5];
  const float* b2     = (const float*)d_in[6];
  const float* w3     = (const float*)d_in[7];
  const float* b3     = (const float*)d_in[8];
  const float* ws1    = (const float*)d_in[9];
  const float* bs1    = (const float*)d_in[10];
  const float* ws2    = (const float*)d_in[11];
  const float* bs2    = (const float*)d_in[12];
  const float* ws3    = (const float*)d_in[13];
  const float* bs3    = (const float*)d_in[14];
  float* outp = (float*)d_out;

  char* ws = (char*)d_ws;
  size_t off = 0;
  auto take = [&](size_t bytes) { char* p = ws + off; off += (bytes + 255) & ~(size_t)255; return p; };
  __bf16* xb   = (__bf16*)take((size_t)TT * DD * 2);
  __bf16* w1b  = (__bf16*)take((size_t)NE * HH * DD * 2);
  __bf16* w3b  = (__bf16*)take((size_t)NE * HH * DD * 2);
  __bf16* w2b  = (__bf16*)take((size_t)NE * DD * HH * 2);
  __bf16* ws1b = (__bf16*)take((size_t)HSH * DD * 2);
  __bf16* ws3b = (__bf16*)take((size_t)HSH * DD * 2);
  __bf16* ws2b = (__bf16*)take((size_t)DD * HSH * 2);
  __bf16* Hbuf = (__bf16*)take((size_t)TT * TOPK * HH * 2);
  __bf16* Sbuf = (__bf16*)take((size_t)TT * HSH * 2);
  float*  cw   = (float*)take((size_t)TT * NE * 4);
  int*    lists  = (int*)take((size_t)NE * TT * 4);
  int*    tok_e  = (int*)take((size_t)TT * TOPK * 4);
  int*    tok_pos= (int*)take((size_t)TT * TOPK * 4);
  int*    counts = (int*)take(64);
  int*    offs   = (int*)take(128);
  // Ybuf (100.7 MB) aliases w1b (115.3 MB): w1b dead after k_g1m completes.
  __bf16* Ybuf = w1b;

  hipMemsetAsync(counts, 0, NE * sizeof(int), stream);

  Cvt7 c;
  const float* srcs[7] = { x, w1, w3, w2, ws1, ws3, ws2 };
  __bf16* dsts[7] = { xb, w1b, w3b, w2b, ws1b, ws3b, ws2b };
  long sz4[7] = { (long)TT * DD / 4, (long)NE * HH * DD / 4, (long)NE * HH * DD / 4,
                  (long)NE * DD * HH / 4, (long)HSH * DD / 4, (long)HSH * DD / 4,
                  (long)DD * HSH / 4 };
  c.off[0] = 0;
  for (int i = 0; i < 7; ++i) { c.src[i] = srcs[i]; c.dst[i] = dsts[i]; c.off[i + 1] = c.off[i] + sz4[i]; }
  k_cvt_all<<<4096, 256, 0, stream>>>(c);

  k_gate<<<TT, 256, 0, stream>>>(x, gate_w, gate_b, cw, counts, lists, tok_e, tok_pos);
  k_offsets<<<1, 64, 0, stream>>>(counts, offs);

  // merged up-proj: z<16 routed (x<22 active), z==16 shared (x<44 active)
  k_g1m<<<dim3(HSH / 64, TT / 128, NE + 1), 256, 0, stream>>>(
      xb, w1b, b1, w3b, b3, ws1b, bs1, ws3b, bs3,
      Hbuf, Sbuf, counts, offs, lists);
  // merged down-proj: z<16 routed -> Ybuf, z==16 shared -> out
  k_g2m<<<dim3(DD / 128, TT / 128, NE + 1), 256, 0, stream>>>(
      Hbuf, Sbuf, w2b, b2, ws2b, bs2, outp, Ybuf, counts, offs);
  // gather-combine routed contributions into out
  k_combine<<<TT, 256, 0, stream>>>(Ybuf, cw, offs, tok_e, tok_pos, outp);
}